// Round 8
// baseline (1328.496 us; speedup 1.0000x reference)
//
#include <hip/hip_runtime.h>

// Problem constants (fixed by the reference)
constexpr int Mdim = 32;      // b*c
constexpr int Kdim = 16384;   // rows*cols
constexpr int Ndim = 16384;   // h*w

constexpr int TPB = 256;

// Tiling: one wave owns 32 n-cols x (Kdim/KT) k. No LDS, no barriers.
constexpr int KT     = 8;               // split-K chunks
constexpr int KC     = Kdim / KT;       // 2048 k per wave
constexpr int SLABS  = KC / 32;         // 64 k32-slabs per wave
constexpr int NT32   = Ndim / 32;       // 512 n-tiles
constexpr int NWAVES = NT32 * KT;       // 4096 waves
constexpr int NBLK   = NWAVES / 4;      // 1024 blocks (4 waves each)

typedef short bf16x8 __attribute__((ext_vector_type(8)));   // 8 bf16 = 16 B
typedef float f32x4  __attribute__((ext_vector_type(4)));

// fp32 -> bf16 RNE (proven R5: absmax 0.0039)
__device__ __forceinline__ short f32_to_bf16(float f) {
    union { float f; unsigned u; } c; c.f = f;
    unsigned u = c.u;
    u += 0x7fffu + ((u >> 16) & 1u);
    return (short)(u >> 16);
}

// ---------------------------------------------------------------------------
// Phase 0: A-fragments of x, MFMA 16x16x32 layout, bf16 (unchanged from R5).
//   A[m = mt*16 + (lane&15)][k = kc*32 + (lane>>4)*8 + j], scaled 1/128.
//   xa[((kc*2+mt)*64 + lane)*8 + j]
// ---------------------------------------------------------------------------
__global__ __launch_bounds__(TPB)
void build_xa(const float* __restrict__ image, short* __restrict__ xa) {
    const int g    = blockIdx.x * TPB + threadIdx.x;
    const int lane = g & 63;
    const int frag = g >> 6;
    const int mt   = frag & 1;
    const int kc   = frag >> 1;
    const int m    = mt * 16 + (lane & 15);
    const int k    = kc * 32 + (lane >> 4) * 8;
    const float* src = image + (size_t)m * Kdim + k;

    bf16x8 o;
    #pragma unroll
    for (int j = 0; j < 8; ++j)
        o[j] = f32_to_bf16(fmaxf(src[j], 0.0f) * (1.0f / 128.0f));
    reinterpret_cast<bf16x8*>(xa)[g] = o;
}

// ---------------------------------------------------------------------------
// Phase 1: barrier-free split-K MFMA GEMM, depth-2 prefetch on BOTH A and B.
// Key fix vs R7: A-fragments are prefetched in the same issue-group as B for
// slab s+2, BEFORE compute(s) consumes slot s's registers. The compiler's
// vmcnt waits then leave the other slot's 18 loads in flight (no vmcnt(0)
// drain per slab -> the pipeline actually pipelines).
// ---------------------------------------------------------------------------
__global__ __launch_bounds__(TPB, 4)
void ht_gemm(const short* __restrict__ xa,    // A-fragments (bf16)
             const float* __restrict__ vote,  // (K, N) fp32
             float* __restrict__ parts)       // (KT, 32, N) fp32 partials
{
    const int tid  = threadIdx.x;
    const int lane = tid & 63;
    const int w    = tid >> 6;
    const int wv   = blockIdx.x * 4 + w;      // 0..4095
    const int nt   = wv & (NT32 - 1);         // n-tile
    const int kch  = wv >> 9;                 // k-chunk
    const int k0   = kch * KC;

    const int bq   = lane >> 4;               // k-quad
    const int bn   = lane & 15;               // n within 16
    const int ncol = nt * 32 + bn;

    f32x4 acc[2][2];                          // [mt][cl]
    #pragma unroll
    for (int a = 0; a < 2; ++a)
        #pragma unroll
        for (int b = 0; b < 2; ++b) { f32x4 z = {0.f, 0.f, 0.f, 0.f}; acc[a][b] = z; }

    const float* vbase = vote + (size_t)(k0 + bq * 8) * Ndim + ncol;
    const short* abase = xa + ((size_t)(k0 >> 5) * 128 + lane) * 8;

    float  b[2][16];                          // depth-2 V slabs (32 VGPRs)
    bf16x8 a[2][2];                           // depth-2 A frags (16 VGPRs)

    auto load_a = [&](int slot, int s) {
        a[slot][0] = *reinterpret_cast<const bf16x8*>(abase + (size_t)s * 1024);
        a[slot][1] = *reinterpret_cast<const bf16x8*>(abase + (size_t)s * 1024 + 512);
    };
    auto load_b = [&](int slot, int s) {
        const float* p = vbase + (size_t)s * 32 * Ndim;
        #pragma unroll
        for (int j = 0; j < 8; ++j) {
            b[slot][j]     = p[(size_t)j * Ndim];        // cl=0: col ncol
            b[slot][8 + j] = p[(size_t)j * Ndim + 16];   // cl=1: col ncol+16
        }
    };
    auto compute = [&](int slot) {
        bf16x8 f0, f1;
        #pragma unroll
        for (int j = 0; j < 8; ++j) {
            f0[j] = f32_to_bf16(b[slot][j]);
            f1[j] = f32_to_bf16(b[slot][8 + j]);
        }
        const bf16x8 a0 = a[slot][0];
        const bf16x8 a1 = a[slot][1];
        acc[0][0] = __builtin_amdgcn_mfma_f32_16x16x32_bf16(a0, f0, acc[0][0], 0, 0, 0);
        acc[1][0] = __builtin_amdgcn_mfma_f32_16x16x32_bf16(a1, f0, acc[1][0], 0, 0, 0);
        acc[0][1] = __builtin_amdgcn_mfma_f32_16x16x32_bf16(a0, f1, acc[0][1], 0, 0, 0);
        acc[1][1] = __builtin_amdgcn_mfma_f32_16x16x32_bf16(a1, f1, acc[1][1], 0, 0, 0);
    };

    load_a(0, 0); load_b(0, 0);               // group G0
    load_a(1, 1); load_b(1, 1);               // group G1
    for (int s = 0; s < SLABS; s += 2) {
        compute(0);                           // waits G0 only (G1 in flight)
        if (s + 2 < SLABS) { load_a(0, s + 2); load_b(0, s + 2); }
        compute(1);                           // waits G1 only (G0' in flight)
        if (s + 3 < SLABS) { load_a(1, s + 3); load_b(1, s + 3); }
    }

    // Epilogue: C/D col = bn, row = bq*4 + r  [R5-verified]
    float* pb = parts + (size_t)kch * ((size_t)Mdim * Ndim);
    #pragma unroll
    for (int mt = 0; mt < 2; ++mt)
        #pragma unroll
        for (int cl = 0; cl < 2; ++cl)
            #pragma unroll
            for (int r = 0; r < 4; ++r) {
                const int row = mt * 16 + bq * 4 + r;
                const int col = nt * 32 + cl * 16 + bn;
                pb[(size_t)row * Ndim + col] = acc[mt][cl][r];
            }
}

// ---------------------------------------------------------------------------
// Phase 2: out[i] = sum_c parts[c][i]
// ---------------------------------------------------------------------------
__global__ __launch_bounds__(TPB)
void ht_reduce(const float* __restrict__ parts, float* __restrict__ out, int nchunks) {
    const size_t i4 = (size_t)blockIdx.x * TPB + threadIdx.x;
    const float4* p = reinterpret_cast<const float4*>(parts) + i4;
    float4 s = make_float4(0.f, 0.f, 0.f, 0.f);
    constexpr size_t stride4 = (size_t)Mdim * Ndim / 4;
    for (int c = 0; c < nchunks; ++c) {
        const float4 v = p[(size_t)c * stride4];
        s.x += v.x; s.y += v.y; s.z += v.z; s.w += v.w;
    }
    reinterpret_cast<float4*>(out)[i4] = s;
}

// ---------------------------------------------------------------------------
// Fallback (tiny ws): fp32 atomic version — correct, slower.
// ---------------------------------------------------------------------------
__global__ __launch_bounds__(TPB)
void ht_gemm_atomic(const float* __restrict__ image, const float* __restrict__ vote,
                    float* __restrict__ out) {
    __shared__ float xsh[256 * Mdim];
    const int tid = threadIdx.x;
    const int ntile = blockIdx.x % 16;
    const int k0 = (blockIdx.x / 16) * 256;
    const int nn0 = ntile * 1024 + tid * 4;
    for (int idx = tid; idx < 256 * Mdim; idx += TPB) {
        const int kk = idx >> 5, m = idx & 31;
        xsh[idx] = fmaxf(image[(size_t)m * Kdim + (k0 + kk)], 0.0f) * (1.0f / 128.0f);
    }
    __syncthreads();
    float4 acc[Mdim];
    #pragma unroll
    for (int m = 0; m < Mdim; ++m) acc[m] = make_float4(0.f, 0.f, 0.f, 0.f);
    const float* vptr = vote + (size_t)k0 * Ndim + nn0;
    for (int kk = 0; kk < 256; ++kk) {
        const float4 v = *reinterpret_cast<const float4*>(vptr);
        vptr += Ndim;
        #pragma unroll
        for (int m = 0; m < Mdim; ++m) {
            const float s = xsh[kk * Mdim + m];
            acc[m].x = fmaf(s, v.x, acc[m].x); acc[m].y = fmaf(s, v.y, acc[m].y);
            acc[m].z = fmaf(s, v.z, acc[m].z); acc[m].w = fmaf(s, v.w, acc[m].w);
        }
    }
    #pragma unroll
    for (int m = 0; m < Mdim; ++m) {
        float* o = out + (size_t)m * Ndim + nn0;
        unsafeAtomicAdd(o + 0, acc[m].x); unsafeAtomicAdd(o + 1, acc[m].y);
        unsafeAtomicAdd(o + 2, acc[m].z); unsafeAtomicAdd(o + 3, acc[m].w);
    }
}

extern "C" void kernel_launch(void* const* d_in, const int* in_sizes, int n_in,
                              void* d_out, int out_size, void* d_ws, size_t ws_size,
                              hipStream_t stream) {
    const float* image = (const float*)d_in[0];   // (32, 16384)
    const float* vote  = (const float*)d_in[1];   // (16384, 16384)
    float* out = (float*)d_out;                   // (32, 16384)

    const size_t xa_bytes    = (size_t)(Kdim / 32) * 2 * 64 * 8 * sizeof(short); // 1 MB
    const size_t chunk_bytes = (size_t)Mdim * Ndim * sizeof(float);              // 2 MB

    if (xa_bytes + (size_t)KT * chunk_bytes > ws_size) {
        (void)hipMemsetAsync(out, 0, (size_t)out_size * sizeof(float), stream);
        ht_gemm_atomic<<<dim3(16 * 64), TPB, 0, stream>>>(image, vote, out);
        return;
    }

    short* xa    = (short*)d_ws;
    float* parts = (float*)((char*)d_ws + xa_bytes);

    build_xa<<<dim3((Kdim / 32) * 2 * 64 / TPB), TPB, 0, stream>>>(image, xa);
    ht_gemm<<<dim3(NBLK), TPB, 0, stream>>>(xa, vote, parts);
    ht_reduce<<<dim3((Mdim * Ndim) / (4 * TPB)), TPB, 0, stream>>>(parts, out, KT);
}

// Round 9
// 1287.857 us; speedup vs baseline: 1.0316x; 1.0316x over previous
//
#include <hip/hip_runtime.h>

// Problem constants (fixed by the reference)
constexpr int Mdim = 32;      // b*c
constexpr int Kdim = 16384;   // rows*cols
constexpr int Ndim = 16384;   // h*w

constexpr int TPB = 256;

// Tiling: wave owns 32 n-cols x KC k, single 32x32x16 MFMA fragment chain.
constexpr int KT     = 8;               // split-K chunks
constexpr int KC     = Kdim / KT;       // 2048 k per wave
constexpr int SLABS  = KC / 16;         // 128 k16-slabs per wave
constexpr int NT32   = Ndim / 32;       // 512 n-tiles
constexpr int NBLK   = NT32 * KT / 4;   // 1024 blocks (4 waves each) = 4/CU
constexpr int DEPTH  = 4;               // slab pipeline depth

typedef short bf16x8 __attribute__((ext_vector_type(8)));   // 8 bf16 = 4 VGPR
typedef float f32x16 __attribute__((ext_vector_type(16)));  // 32x32 C/D frag

// fp32 -> bf16 RNE (proven R5+: absmax 0.0039)
__device__ __forceinline__ short f32_to_bf16(float f) {
    union { float f; unsigned u; } c; c.f = f;
    unsigned u = c.u;
    u += 0x7fffu + ((u >> 16) & 1u);
    return (short)(u >> 16);
}

// ---------------------------------------------------------------------------
// Phase 0: A-fragments of x for 32x32x16 MFMA, bf16, scaled 1/128.
//   slab = k/16; lane holds A[m = lane&31][k = slab*16 + (lane>>5)*8 + j]
//   xa[(slab*64 + lane)*8 + j]
// ---------------------------------------------------------------------------
__global__ __launch_bounds__(TPB)
void build_xa(const float* __restrict__ image, short* __restrict__ xa) {
    const int g    = blockIdx.x * TPB + threadIdx.x;   // 0 .. 65535
    const int lane = g & 63;
    const int slab = g >> 6;                           // 0 .. 1023
    const int m    = lane & 31;
    const int k    = slab * 16 + (lane >> 5) * 8;
    const float* src = image + (size_t)m * Kdim + k;

    bf16x8 o;
    #pragma unroll
    for (int j = 0; j < 8; ++j)
        o[j] = f32_to_bf16(fmaxf(src[j], 0.0f) * (1.0f / 128.0f));
    reinterpret_cast<bf16x8*>(xa)[g] = o;
}

// ---------------------------------------------------------------------------
// Phase 1: barrier-free split-K GEMM, one 32x32x16 MFMA per 16-k slab.
// B loaded straight from global V: per load instr, 2 k-rows x 128 B full
// lines (col = lane&31 contiguous). Depth-4 slab pipeline on vmcnt only.
// ---------------------------------------------------------------------------
__global__ __launch_bounds__(TPB, 4)
void ht_gemm(const short* __restrict__ xa,    // A-fragments (bf16)
             const float* __restrict__ vote,  // (K, N) fp32
             float* __restrict__ parts)       // (KT, 32, N) fp32 partials
{
    const int tid  = threadIdx.x;
    const int lane = tid & 63;
    const int w    = tid >> 6;
    const int wv   = blockIdx.x * 4 + w;      // 0..4095
    const int nt   = wv & (NT32 - 1);         // n-tile
    const int kch  = wv >> 9;                 // k-chunk
    const int k0   = kch * KC;

    const int col  = nt * 32 + (lane & 31);
    const int krow = (lane >> 5) * 8;         // 0 or 8 within slab

    const float* vbase = vote + (size_t)(k0 + krow) * Ndim + col;
    const short* abase = xa + ((size_t)(k0 / 16) * 64 + lane) * 8;

    f32x16 acc;
    #pragma unroll
    for (int i = 0; i < 16; ++i) acc[i] = 0.0f;

    float  bv[DEPTH][8];                      // 32 VGPRs of in-flight V
    bf16x8 av[DEPTH];                         // 16 VGPRs of in-flight A

    auto load = [&](int slot, int s) {
        const float* p = vbase + (size_t)s * 16 * Ndim;
        #pragma unroll
        for (int j = 0; j < 8; ++j)
            bv[slot][j] = __builtin_nontemporal_load(p + (size_t)j * Ndim);
        av[slot] = *reinterpret_cast<const bf16x8*>(abase + (size_t)s * 512);
    };
    auto comp = [&](int slot) {
        bf16x8 f;
        #pragma unroll
        for (int j = 0; j < 8; ++j) f[j] = f32_to_bf16(bv[slot][j]);
        acc = __builtin_amdgcn_mfma_f32_32x32x16_bf16(av[slot], f, acc, 0, 0, 0);
    };

    #pragma unroll
    for (int u = 0; u < DEPTH; ++u) load(u, u);
    for (int s = 0; s < SLABS; s += DEPTH) {
        #pragma unroll
        for (int u = 0; u < DEPTH; ++u) {
            comp(u);                                   // waits only slab s+u's group
            if (s + DEPTH + u < SLABS) load(u, s + DEPTH + u);
        }
    }

    // Epilogue: C/D col = lane&31, row = (reg&3) + 8*(reg>>2) + 4*(lane>>5)
    // [m74/m101-verified]. Each store: 2 x 128 B contiguous segments.
    float* pb = parts + (size_t)kch * ((size_t)Mdim * Ndim);
    const int rbase = 4 * (lane >> 5);
    #pragma unroll
    for (int r = 0; r < 16; ++r) {
        const int row = (r & 3) + 8 * (r >> 2) + rbase;
        pb[(size_t)row * Ndim + col] = acc[r];
    }
}

// ---------------------------------------------------------------------------
// Phase 2: out[i] = sum_c parts[c][i]
// ---------------------------------------------------------------------------
__global__ __launch_bounds__(TPB)
void ht_reduce(const float* __restrict__ parts, float* __restrict__ out, int nchunks) {
    const size_t i4 = (size_t)blockIdx.x * TPB + threadIdx.x;
    const float4* p = reinterpret_cast<const float4*>(parts) + i4;
    float4 s = make_float4(0.f, 0.f, 0.f, 0.f);
    constexpr size_t stride4 = (size_t)Mdim * Ndim / 4;
    for (int c = 0; c < nchunks; ++c) {
        const float4 v = p[(size_t)c * stride4];
        s.x += v.x; s.y += v.y; s.z += v.z; s.w += v.w;
    }
    reinterpret_cast<float4*>(out)[i4] = s;
}

// ---------------------------------------------------------------------------
// Fallback (tiny ws): fp32 atomic version — correct, slower.
// ---------------------------------------------------------------------------
__global__ __launch_bounds__(TPB)
void ht_gemm_atomic(const float* __restrict__ image, const float* __restrict__ vote,
                    float* __restrict__ out) {
    __shared__ float xsh[256 * Mdim];
    const int tid = threadIdx.x;
    const int ntile = blockIdx.x % 16;
    const int k0 = (blockIdx.x / 16) * 256;
    const int nn0 = ntile * 1024 + tid * 4;
    for (int idx = tid; idx < 256 * Mdim; idx += TPB) {
        const int kk = idx >> 5, m = idx & 31;
        xsh[idx] = fmaxf(image[(size_t)m * Kdim + (k0 + kk)], 0.0f) * (1.0f / 128.0f);
    }
    __syncthreads();
    float4 acc[Mdim];
    #pragma unroll
    for (int m = 0; m < Mdim; ++m) acc[m] = make_float4(0.f, 0.f, 0.f, 0.f);
    const float* vptr = vote + (size_t)k0 * Ndim + nn0;
    for (int kk = 0; kk < 256; ++kk) {
        const float4 v = *reinterpret_cast<const float4*>(vptr);
        vptr += Ndim;
        #pragma unroll
        for (int m = 0; m < Mdim; ++m) {
            const float s = xsh[kk * Mdim + m];
            acc[m].x = fmaf(s, v.x, acc[m].x); acc[m].y = fmaf(s, v.y, acc[m].y);
            acc[m].z = fmaf(s, v.z, acc[m].z); acc[m].w = fmaf(s, v.w, acc[m].w);
        }
    }
    #pragma unroll
    for (int m = 0; m < Mdim; ++m) {
        float* o = out + (size_t)m * Ndim + nn0;
        unsafeAtomicAdd(o + 0, acc[m].x); unsafeAtomicAdd(o + 1, acc[m].y);
        unsafeAtomicAdd(o + 2, acc[m].z); unsafeAtomicAdd(o + 3, acc[m].w);
    }
}

extern "C" void kernel_launch(void* const* d_in, const int* in_sizes, int n_in,
                              void* d_out, int out_size, void* d_ws, size_t ws_size,
                              hipStream_t stream) {
    const float* image = (const float*)d_in[0];   // (32, 16384)
    const float* vote  = (const float*)d_in[1];   // (16384, 16384)
    float* out = (float*)d_out;                   // (32, 16384)

    const size_t xa_bytes    = (size_t)(Kdim / 16) * 64 * 8 * sizeof(short);   // 1 MB
    const size_t chunk_bytes = (size_t)Mdim * Ndim * sizeof(float);            // 2 MB

    if (xa_bytes + (size_t)KT * chunk_bytes > ws_size) {
        (void)hipMemsetAsync(out, 0, (size_t)out_size * sizeof(float), stream);
        ht_gemm_atomic<<<dim3(16 * 64), TPB, 0, stream>>>(image, vote, out);
        return;
    }

    short* xa    = (short*)d_ws;
    float* parts = (float*)((char*)d_ws + xa_bytes);

    build_xa<<<dim3((Kdim / 16) * 64 / TPB), TPB, 0, stream>>>(image, xa);
    ht_gemm<<<dim3(NBLK), TPB, 0, stream>>>(xa, vote, parts);
    ht_reduce<<<dim3((Mdim * Ndim) / (4 * TPB)), TPB, 0, stream>>>(parts, out, KT);
}